// Round 7
// baseline (374.367 us; speedup 1.0000x reference)
//
#include <hip/hip_runtime.h>
#include <cmath>

// ---------------------------------------------------------------------------
// GNNPooling: 3x (ChebConv -> BN(train) -> ReLU) -> mean over nodes.
// Lhat = alpha*I + beta*J  =>  y[b] = A_b @ WI + 1 * colsum(A_b @ WJ)
// One wave = one batch (64 rows x 128 cols). Layer1 stages its A-chunks
// through a wave-private XOR-swizzled LDS slab (coalesced 128B-line loads,
// conflict-free b128 frag reads, double-buffered, issue-early/write-late).
// Layers 2/3 read y as pre-swizzled bf16 granules (1KB contiguous per load).
// ---------------------------------------------------------------------------

typedef __attribute__((ext_vector_type(8))) short bf16x8;
typedef __attribute__((ext_vector_type(4))) float f32x4;

constexpr int BATCH = 4096;
constexpr int DCH   = 128;
constexpr float INV_NROWS = 1.0f / 262144.0f;

// workspace offsets (in floats)
constexpr size_t OFF_G1   = 0;            // layer1 WI+WJ granules: 32768 floats
constexpr size_t OFF_G2   = 32768;        // 16384 floats
constexpr size_t OFF_G3   = 49152;        // 16384 floats
constexpr size_t OFF_SCSH = 65536;        // 3 * 256 (sc[128], sh[128] per layer)
constexpr size_t OFF_PP2  = 66304;        // 256*256 stage-A partials
constexpr size_t OFF_PART = 131840;       // 4096*256 per-batch partials
constexpr size_t OFF_Y    = 1180416;      // y bf16: 4096*64*128 ushorts

struct Coeffs { float a[5]; float b[5]; };

__device__ __forceinline__ unsigned short f2bf(float f) {
  unsigned u = __float_as_uint(f);
  u += 0x7FFFu + ((u >> 16) & 1u);        // round-to-nearest-even
  return (unsigned short)(u >> 16);
}
__device__ __forceinline__ float bf2f(unsigned short s) {
  return __uint_as_float(((unsigned)s) << 16);
}

// ---------------------------------------------------------------------------
// prep_gran: WI (= sum_k a_k W_k) and WJ (= sum_k b_k W_k) in B-fragment
// granule order, bf16. unit r = kt*512 + ct*64 + lane holds 8 values
// W[kt*32+(lane>>4)*8+i][ct*16+(lane&15)].
// ---------------------------------------------------------------------------
__global__ __launch_bounds__(256) void prep_gran(const float* __restrict__ W1,
                                                 const float* __restrict__ W2,
                                                 const float* __restrict__ W3,
                                                 float* __restrict__ ws, Coeffs co)
{
  int id = blockIdx.x * 256 + threadIdx.x;       // 0..16383
  const float* W; int CIN, K, r; const float* cf; unsigned short* dst;
  if (id < 8192) {
    W = W1; CIN = 256; K = 5; r = id & 4095;
    cf = (id >= 4096) ? co.b : co.a;
    dst = (unsigned short*)(ws + OFF_G1) + (size_t)id * 8;
  } else if (id < 12288) {
    int e = id - 8192; W = W2; CIN = 128; K = 3; r = e & 2047;
    cf = (e >= 2048) ? co.b : co.a;
    dst = (unsigned short*)(ws + OFF_G2) + (size_t)e * 8;
  } else {
    int e = id - 12288; W = W3; CIN = 128; K = 3; r = e & 2047;
    cf = (e >= 2048) ? co.b : co.a;
    dst = (unsigned short*)(ws + OFF_G3) + (size_t)e * 8;
  }
  int kt  = r >> 9;
  int ct  = (r >> 6) & 7;
  int ln  = r & 63;
  int col = ct * 16 + (ln & 15);
  int f0  = kt * 32 + (ln >> 4) * 8;
  bf16x8 g;
#pragma unroll
  for (int i = 0; i < 8; ++i) {
    float s = 0.f;
    for (int k = 0; k < K; ++k)
      s = fmaf(cf[k], W[((size_t)k * CIN + f0 + i) * DCH + col], s);
    g[i] = (short)f2bf(s);
  }
  *reinterpret_cast<bf16x8*>(dst) = g;
}

// ---------------------------------------------------------------------------
// Fused layer: block = 4 waves = 4 batches; wave owns all 64 rows of its batch.
// ---------------------------------------------------------------------------
template <int CIN, bool FIRST>
__global__ __launch_bounds__(256, 2) void layer_k(
    const float* __restrict__ inF,              // FIRST: x (row-major fp32)
    const unsigned short* __restrict__ inB,     // !FIRST: y bf16 granules
    unsigned short* __restrict__ yout,          // y bf16 granules
    const unsigned short* __restrict__ gran,    // WI then WJ granules (bf16)
    const float* __restrict__ scsh,             // [2][128] BN scale/shift or null
    float* __restrict__ part)                   // [4096][256] per-batch partials
{
  constexpr int NKT = CIN / 32;
  constexpr int NG  = CIN * 16;                 // granule units per matrix

  // 18KB per wave: FIRST staging dbuf (2 x 8KB = 4096 floats) + epilogue reuse
  __shared__ float sSlab[4][4608];

  const int tid = threadIdx.x;
  const int w   = tid >> 6;
  const int l   = tid & 63;
  const int lr  = l & 15;
  const int lk  = l >> 4;
  const int batch = blockIdx.x * 4 + w;

  float* slab = sSlab[w];

  f32x4 acc[8][4];                              // [ct][mt]
  f32x4 accJ[8];
#pragma unroll
  for (int ct = 0; ct < 8; ++ct) {
#pragma unroll
    for (int mt = 0; mt < 4; ++mt)
#pragma unroll
      for (int r = 0; r < 4; ++r) acc[ct][mt][r] = 0.f;
#pragma unroll
    for (int r = 0; r < 4; ++r) accJ[ct][r] = 0.f;
  }

  const bf16x8* gI = reinterpret_cast<const bf16x8*>(gran) + l;
  const bf16x8* gJ = gI + NG;

  // staging lane roles (FIRST): chunk lb of row (sweep*8 + la); 128B lines fully used
  const int lb = l & 7;
  const int la = l >> 3;
  const float* xb = FIRST ? (inF + (size_t)batch * 64 * 256) : nullptr;

  float4 ldbuf[FIRST ? 8 : 1];
  if constexpr (FIRST) {
    // prologue: stage kt=0 into buf0 (LDS slot = chunk ^ (row&7), bijective)
#pragma unroll
    for (int s = 0; s < 8; ++s) {
      const int r = s * 8 + la;
      ldbuf[s] = *reinterpret_cast<const float4*>(xb + (size_t)r * CIN + lb * 4);
    }
#pragma unroll
    for (int s = 0; s < 8; ++s) {
      const int r = s * 8 + la;
      *reinterpret_cast<float4*>(slab + r * 32 + ((lb ^ (r & 7)) * 4)) = ldbuf[s];
    }
  }

#pragma unroll
  for (int kt = 0; kt < NKT; ++kt) {
    // ---- issue next-kt global loads early (latency hides under MFMAs) ----
    if constexpr (FIRST) {
      if (kt + 1 < NKT) {
#pragma unroll
        for (int s = 0; s < 8; ++s) {
          const int r = s * 8 + la;
          ldbuf[s] = *reinterpret_cast<const float4*>(
              xb + (size_t)r * CIN + (kt + 1) * 32 + lb * 4);
        }
      }
    }

    bf16x8 af[4];
    float vs[8];
#pragma unroll
    for (int i = 0; i < 8; ++i) vs[i] = 0.f;

    if constexpr (FIRST) {
      // ---- fragments from swizzled LDS (b128-minimum bank aliasing) ----
      const float* sc = slab + (kt & 1) * 2048;
#pragma unroll
      for (int mt = 0; mt < 4; ++mt) {
        const int row = mt * 16 + lr;
        const int rb  = row * 32;
        float4 f0 = *reinterpret_cast<const float4*>(sc + rb + (((2 * lk)     ^ (lr & 7)) * 4));
        float4 f1 = *reinterpret_cast<const float4*>(sc + rb + (((2 * lk + 1) ^ (lr & 7)) * 4));
        float v8[8] = {f0.x, f0.y, f0.z, f0.w, f1.x, f1.y, f1.z, f1.w};
#pragma unroll
        for (int i = 0; i < 8; ++i) {
          vs[i] += v8[i];
          af[mt][i] = (short)f2bf(v8[i]);
        }
      }
    } else {
      const int c0 = kt * 32 + lk * 8;
      const float4 s0 = *reinterpret_cast<const float4*>(scsh + c0);
      const float4 s1 = *reinterpret_cast<const float4*>(scsh + c0 + 4);
      const float4 h0 = *reinterpret_cast<const float4*>(scsh + 128 + c0);
      const float4 h1 = *reinterpret_cast<const float4*>(scsh + 128 + c0 + 4);
      const float scv[8] = {s0.x, s0.y, s0.z, s0.w, s1.x, s1.y, s1.z, s1.w};
      const float shv[8] = {h0.x, h0.y, h0.z, h0.w, h1.x, h1.y, h1.z, h1.w};
      const bf16x8* yb = reinterpret_cast<const bf16x8*>(inB + (size_t)batch * 8192);
#pragma unroll
      for (int mt = 0; mt < 4; ++mt) {
        bf16x8 r16 = yb[kt * 256 + mt * 64 + l];
#pragma unroll
        for (int i = 0; i < 8; ++i) {
          float hv = fmaxf(fmaf(bf2f((unsigned short)r16[i]), scv[i], shv[i]), 0.f);
          vs[i] += hv;
          af[mt][i] = (short)f2bf(hv);
        }
      }
    }

    bf16x8 asum;
#pragma unroll
    for (int i = 0; i < 8; ++i) asum[i] = (short)f2bf(vs[i]);

    const bf16x8* bI = gI + (size_t)kt * 512;
#pragma unroll
    for (int ct = 0; ct < 8; ++ct) {
      bf16x8 bfr = bI[ct * 64];
#pragma unroll
      for (int mt = 0; mt < 4; ++mt)
        acc[ct][mt] = __builtin_amdgcn_mfma_f32_16x16x32_bf16(af[mt], bfr, acc[ct][mt], 0, 0, 0);
    }
    const bf16x8* bJ = gJ + (size_t)kt * 512;
#pragma unroll
    for (int ct = 0; ct < 8; ++ct)
      accJ[ct] = __builtin_amdgcn_mfma_f32_16x16x32_bf16(asum, bJ[ct * 64], accJ[ct], 0, 0, 0);

    // ---- write-late: stage kt+1 into the other buffer after the MFMAs ----
    if constexpr (FIRST) {
      if (kt + 1 < NKT) {
        __builtin_amdgcn_sched_barrier(0);
        float* sn = slab + ((kt + 1) & 1) * 2048;
#pragma unroll
        for (int s = 0; s < 8; ++s) {
          const int r = s * 8 + la;
          *reinterpret_cast<float4*>(sn + r * 32 + ((lb ^ (r & 7)) * 4)) = ldbuf[s];
        }
      }
    }
  }

  // J vector: colsum over accJ's 16 pseudo-rows -> every lane holds jv for its lr
  float jv[8];
#pragma unroll
  for (int ct = 0; ct < 8; ++ct) {
    float t = (accJ[ct][0] + accJ[ct][1]) + (accJ[ct][2] + accJ[ct][3]);
    t += __shfl_xor(t, 16);
    t += __shfl_xor(t, 32);
    jv[ct] = t;
  }

  // epilogue (wave-private, no barriers): add J, bf16 -> LDS slab, BN partials
  unsigned short* my = reinterpret_cast<unsigned short*>(slab);
  float psum[8], psq[8];
#pragma unroll
  for (int ct = 0; ct < 8; ++ct) { psum[ct] = 0.f; psq[ct] = 0.f; }

#pragma unroll
  for (int ct = 0; ct < 8; ++ct)
#pragma unroll
    for (int mt = 0; mt < 4; ++mt)
#pragma unroll
      for (int r = 0; r < 4; ++r) {
        float val = acc[ct][mt][r] + jv[ct];
        psum[ct] += val;
        psq[ct]  = fmaf(val, val, psq[ct]);
        my[(mt * 16 + lk * 4 + r) * 136 + ct * 16 + lr] = f2bf(val);
      }

  // granule store: contiguous 1KB per instruction per wave
  bf16x8* yo = reinterpret_cast<bf16x8*>(yout + (size_t)batch * 8192);
#pragma unroll
  for (int kt2 = 0; kt2 < 4; ++kt2)
#pragma unroll
    for (int mt = 0; mt < 4; ++mt) {
      bf16x8 gd = *reinterpret_cast<const bf16x8*>(&my[(mt * 16 + lr) * 136 + kt2 * 32 + lk * 8]);
      yo[kt2 * 256 + mt * 64 + l] = gd;
    }

  // per-batch BN partials: reduce over lk with 2 shuffles, coalesced store
#pragma unroll
  for (int ct = 0; ct < 8; ++ct) {
    psum[ct] += __shfl_xor(psum[ct], 16);
    psum[ct] += __shfl_xor(psum[ct], 32);
    psq[ct]  += __shfl_xor(psq[ct], 16);
    psq[ct]  += __shfl_xor(psq[ct], 32);
  }
  if (lk == 0) {
    float* pb = part + (size_t)batch * 256;
#pragma unroll
    for (int ct = 0; ct < 8; ++ct) {
      pb[ct * 16 + lr]       = psum[ct];
      pb[128 + ct * 16 + lr] = psq[ct];
    }
  }
}

// ---------------------------------------------------------------------------
// Reduction of part[4096][256] -> scsh[2][128] (two coalesced stages)
// ---------------------------------------------------------------------------
__global__ __launch_bounds__(256) void finA_k(const float* __restrict__ part,
                                              float* __restrict__ pp2)
{
  const int g = blockIdx.x;                     // 0..255
  float s = 0.f;
#pragma unroll
  for (int i = 0; i < 16; ++i)
    s += part[(size_t)(g * 16 + i) * 256 + threadIdx.x];
  pp2[(size_t)g * 256 + threadIdx.x] = s;
}

__global__ __launch_bounds__(1024) void finB_k(const float* __restrict__ pp2,
                                               const float* __restrict__ gam,
                                               const float* __restrict__ bet,
                                               float* __restrict__ scsh)
{
  __shared__ float red[4][256];
  __shared__ float tot[256];
  const int q = threadIdx.x >> 8, t = threadIdx.x & 255;
  float s = 0.f;
#pragma unroll 8
  for (int i = 0; i < 64; ++i)
    s += pp2[(size_t)(q * 64 + i) * 256 + t];
  red[q][t] = s;
  __syncthreads();
  if (q == 0) tot[t] = (red[0][t] + red[1][t]) + (red[2][t] + red[3][t]);
  __syncthreads();
  if (threadIdx.x < 128) {
    float mu  = tot[threadIdx.x] * INV_NROWS;
    float var = tot[128 + threadIdx.x] * INV_NROWS - mu * mu;
    float rs  = rsqrtf(var + 1e-5f);
    float sc  = gam[threadIdx.x] * rs;
    scsh[threadIdx.x]       = sc;
    scsh[128 + threadIdx.x] = fmaf(-mu, sc, bet[threadIdx.x]);
  }
}

// ---------------------------------------------------------------------------
// Final BN + ReLU + mean over nodes (reads bf16 granules, uses scsh)
// ---------------------------------------------------------------------------
__global__ __launch_bounds__(256) void pool_k(const unsigned short* __restrict__ y,
                                              const float* __restrict__ scsh,
                                              float* __restrict__ out)
{
  __shared__ float sYp[64][132];
  __shared__ float sPool[2][DCH];
  const int b = blockIdx.x;
  const int t = threadIdx.x;
  const int wv = t >> 6, l = t & 63;
  const int row = wv * 16 + (l & 15);

#pragma unroll
  for (int kt = 0; kt < 4; ++kt) {
    bf16x8 r16 = *(reinterpret_cast<const bf16x8*>(y + (size_t)b * 8192) + (kt * 256 + t));
    const int feat = kt * 32 + (l >> 4) * 8;
    float4 f0, f1;
    f0.x = bf2f((unsigned short)r16[0]); f0.y = bf2f((unsigned short)r16[1]);
    f0.z = bf2f((unsigned short)r16[2]); f0.w = bf2f((unsigned short)r16[3]);
    f1.x = bf2f((unsigned short)r16[4]); f1.y = bf2f((unsigned short)r16[5]);
    f1.z = bf2f((unsigned short)r16[6]); f1.w = bf2f((unsigned short)r16[7]);
    *reinterpret_cast<float4*>(&sYp[row][feat])     = f0;
    *reinterpret_cast<float4*>(&sYp[row][feat + 4]) = f1;
  }
  __syncthreads();
  {
    const int c = t & 127, rg = t >> 7;
    float sc = scsh[c];
    float sh = scsh[128 + c];
    float s = 0.f;
#pragma unroll 8
    for (int r = rg * 32; r < rg * 32 + 32; ++r)
      s += fmaxf(fmaf(sYp[r][c], sc, sh), 0.f);
    sPool[rg][c] = s;
  }
  __syncthreads();
  if (t < DCH)
    out[(size_t)b * DCH + t] = (sPool[0][t] + sPool[1][t]) * (1.0f / 64.0f);
}

// ---------------------------------------------------------------------------
extern "C" void kernel_launch(void* const* d_in, const int* in_sizes, int n_in,
                              void* d_out, int out_size, void* d_ws, size_t ws_size,
                              hipStream_t stream)
{
  const float* x  = (const float*)d_in[0];
  const float* W1 = (const float*)d_in[1];
  const float* W2 = (const float*)d_in[2];
  const float* W3 = (const float*)d_in[3];
  const float* g1 = (const float*)d_in[4];
  const float* b1 = (const float*)d_in[5];
  const float* g2 = (const float*)d_in[6];
  const float* b2 = (const float*)d_in[7];
  const float* g3 = (const float*)d_in[8];
  const float* b3 = (const float*)d_in[9];
  float* out = (float*)d_out;
  float* ws  = (float*)d_ws;

  Coeffs co;
  {
    double sd  = sqrt(63.0 / 4095.0);
    double av  = exp(-1.0 / sd);
    double deg = 1.0 + 63.0 * av;
    double al  = -(1.0 - av) / deg;
    double be  = -av / deg;
    double ak[5], bk[5];
    ak[0] = 1.0; bk[0] = 0.0;
    ak[1] = al;  bk[1] = be;
    for (int k = 2; k < 5; ++k) {
      ak[k] = 2.0 * al * ak[k - 1] - ak[k - 2];
      bk[k] = 2.0 * (be * ak[k - 1] + (al + 64.0 * be) * bk[k - 1]) - bk[k - 2];
    }
    for (int k = 0; k < 5; ++k) { co.a[k] = (float)ak[k]; co.b[k] = (float)bk[k]; }
  }

  const unsigned short* gr1 = (const unsigned short*)(ws + OFF_G1);
  const unsigned short* gr2 = (const unsigned short*)(ws + OFF_G2);
  const unsigned short* gr3 = (const unsigned short*)(ws + OFF_G3);
  float* scsh1 = ws + OFF_SCSH;
  float* scsh2 = scsh1 + 256;
  float* scsh3 = scsh1 + 512;
  float* pp2   = ws + OFF_PP2;
  float* pp    = ws + OFF_PART;
  unsigned short* yv = (unsigned short*)(ws + OFF_Y);

  prep_gran<<<64, 256, 0, stream>>>(W1, W2, W3, ws, co);

  layer_k<256, true ><<<1024, 256, 0, stream>>>(x, nullptr, yv, gr1, nullptr, pp);
  finA_k<<<256, 256, 0, stream>>>(pp, pp2);
  finB_k<<<1, 1024, 0, stream>>>(pp2, g1, b1, scsh1);
  layer_k<128, false><<<1024, 256, 0, stream>>>(nullptr, yv, yv, gr2, scsh1, pp);
  finA_k<<<256, 256, 0, stream>>>(pp, pp2);
  finB_k<<<1, 1024, 0, stream>>>(pp2, g2, b2, scsh2);
  layer_k<128, false><<<1024, 256, 0, stream>>>(nullptr, yv, yv, gr3, scsh2, pp);
  finA_k<<<256, 256, 0, stream>>>(pp, pp2);
  finB_k<<<1, 1024, 0, stream>>>(pp2, g3, b3, scsh3);
  pool_k<<<BATCH, 256, 0, stream>>>(yv, scsh3, out);

  (void)in_sizes; (void)n_in; (void)out_size; (void)ws_size;
}

// Round 8
// 216.689 us; speedup vs baseline: 1.7277x; 1.7277x over previous
//
#include <hip/hip_runtime.h>
#include <cmath>

// ---------------------------------------------------------------------------
// GNNPooling: 3x (ChebConv -> BN(train) -> ReLU) -> mean over nodes.
// Lhat = alpha*I + beta*J  =>  y[b] = A_b @ WI + 1 * colsum(A_b @ WJ)
// Round 8: B (WI+WJ granules) staged in LDS ONCE per block (global_load_lds),
// block = 16 batches; each of 4 waves streams 4 batches sequentially with all
// 64 rows per wave (B:A ratio amortized; LDS demand << HBM floor). Only global
// traffic in steady state: streaming A reads + y granule writes. One barrier
// total (after staging). Epilogue transposes via per-wave 16-row LDS chunks.
// ---------------------------------------------------------------------------

typedef __attribute__((ext_vector_type(8))) short bf16x8;
typedef __attribute__((ext_vector_type(4))) float f32x4;

typedef __attribute__((address_space(1))) const unsigned int guint_t;
typedef __attribute__((address_space(3))) unsigned int luint_t;

constexpr int BATCH = 4096;
constexpr int DCH   = 128;
constexpr float INV_NROWS = 1.0f / 262144.0f;

// workspace offsets (in floats)
constexpr size_t OFF_G1   = 0;            // layer1 WI+WJ granules: 32768 floats
constexpr size_t OFF_G2   = 32768;        // 16384 floats
constexpr size_t OFF_G3   = 49152;        // 16384 floats
constexpr size_t OFF_SCSH = 65536;        // 3 * 256 (sc[128], sh[128] per layer)
constexpr size_t OFF_PP2  = 66304;        // 256*256 stage-A partials
constexpr size_t OFF_PART = 131840;       // 4096*256 per-batch partials
constexpr size_t OFF_Y    = 1180416;      // y bf16: 4096*64*128 ushorts

struct Coeffs { float a[5]; float b[5]; };

__device__ __forceinline__ unsigned short f2bf(float f) {
  unsigned u = __float_as_uint(f);
  u += 0x7FFFu + ((u >> 16) & 1u);        // round-to-nearest-even
  return (unsigned short)(u >> 16);
}
__device__ __forceinline__ float bf2f(unsigned short s) {
  return __uint_as_float(((unsigned)s) << 16);
}

// ---------------------------------------------------------------------------
// prep_gran: WI (= sum_k a_k W_k) and WJ (= sum_k b_k W_k) in B-fragment
// granule order, bf16. unit r = kt*512 + ct*64 + lane holds 8 values
// W[kt*32+(lane>>4)*8+i][ct*16+(lane&15)].
// ---------------------------------------------------------------------------
__global__ __launch_bounds__(256) void prep_gran(const float* __restrict__ W1,
                                                 const float* __restrict__ W2,
                                                 const float* __restrict__ W3,
                                                 float* __restrict__ ws, Coeffs co)
{
  int id = blockIdx.x * 256 + threadIdx.x;       // 0..16383
  const float* W; int CIN, K, r; const float* cf; unsigned short* dst;
  if (id < 8192) {
    W = W1; CIN = 256; K = 5; r = id & 4095;
    cf = (id >= 4096) ? co.b : co.a;
    dst = (unsigned short*)(ws + OFF_G1) + (size_t)id * 8;
  } else if (id < 12288) {
    int e = id - 8192; W = W2; CIN = 128; K = 3; r = e & 2047;
    cf = (e >= 2048) ? co.b : co.a;
    dst = (unsigned short*)(ws + OFF_G2) + (size_t)e * 8;
  } else {
    int e = id - 12288; W = W3; CIN = 128; K = 3; r = e & 2047;
    cf = (e >= 2048) ? co.b : co.a;
    dst = (unsigned short*)(ws + OFF_G3) + (size_t)e * 8;
  }
  int kt  = r >> 9;
  int ct  = (r >> 6) & 7;
  int ln  = r & 63;
  int col = ct * 16 + (ln & 15);
  int f0  = kt * 32 + (ln >> 4) * 8;
  bf16x8 g;
#pragma unroll
  for (int i = 0; i < 8; ++i) {
    float s = 0.f;
    for (int k = 0; k < K; ++k)
      s = fmaf(cf[k], W[((size_t)k * CIN + f0 + i) * DCH + col], s);
    g[i] = (short)f2bf(s);
  }
  *reinterpret_cast<bf16x8*>(dst) = g;
}

// ---------------------------------------------------------------------------
// Fused layer: block = 16 batches; wave w handles batches it*4+w, it=0..3,
// all 64 rows each. B lives in LDS for the whole kernel.
// ---------------------------------------------------------------------------
template <int CIN, bool FIRST>
__global__ __launch_bounds__(256) void layer_k(
    const float* __restrict__ inF,              // FIRST: x (row-major fp32)
    const unsigned short* __restrict__ inB,     // !FIRST: y bf16 granules
    unsigned short* __restrict__ yout,          // y bf16 granules
    const unsigned short* __restrict__ gran,    // WI then WJ granules (bf16)
    const float* __restrict__ scsh,             // [2][128] BN scale/shift or null
    float* __restrict__ part)                   // [4096][256] per-batch partials
{
  constexpr int NKT    = CIN / 32;
  constexpr int NG     = CIN * 16;              // bf16x8 units per matrix
  constexpr int BBYTES = CIN * 512;             // WI+WJ bytes

  __shared__ unsigned short sB[BBYTES / 2];     // staged WI+WJ granules
  __shared__ unsigned short sT[4][16 * 136];    // per-wave transpose chunk
  __shared__ float sScale[DCH];
  __shared__ float sShift[DCH];

  const int tid = threadIdx.x;
  const int w   = tid >> 6;
  const int l   = tid & 63;
  const int lr  = l & 15;
  const int lk  = l >> 4;

  // ---- stage B once: linear global_load_lds, 4 waves x 1KB per round ----
  {
    const char* gB = reinterpret_cast<const char*>(gran);
    char* lB = reinterpret_cast<char*>(&sB[0]);
#pragma unroll
    for (int i = 0; i < BBYTES / 4096; ++i) {
      const int c = i * 4 + w;
      __builtin_amdgcn_global_load_lds(
          (guint_t*)(gB + (size_t)c * 1024 + (size_t)l * 16),
          (luint_t*)(lB + c * 1024), 16, 0, 0);
    }
  }
  if constexpr (!FIRST) {
    if (tid < DCH) {
      sScale[tid] = scsh[tid];
      sShift[tid] = scsh[DCH + tid];
    }
  }
  __syncthreads();                              // drains staging

  const bf16x8* sBu = reinterpret_cast<const bf16x8*>(&sB[0]);

#pragma unroll 1
  for (int it = 0; it < 4; ++it) {
    const int batch = blockIdx.x * 16 + it * 4 + w;

    f32x4 acc[8][4];                            // [ct][mt]
    f32x4 accJ[8];
#pragma unroll
    for (int ct = 0; ct < 8; ++ct) {
#pragma unroll
      for (int mt = 0; mt < 4; ++mt)
#pragma unroll
        for (int r = 0; r < 4; ++r) acc[ct][mt][r] = 0.f;
#pragma unroll
      for (int r = 0; r < 4; ++r) accJ[ct][r] = 0.f;
    }

#pragma unroll
    for (int kt = 0; kt < NKT; ++kt) {
      bf16x8 af[4];
      float vs[8];
#pragma unroll
      for (int i = 0; i < 8; ++i) vs[i] = 0.f;

      if constexpr (FIRST) {
        const float* ap = inF + ((size_t)batch * 64 + lr) * CIN + kt * 32 + lk * 8;
#pragma unroll
        for (int mt = 0; mt < 4; ++mt) {
          float4 u0 = *reinterpret_cast<const float4*>(ap + (size_t)mt * 16 * CIN);
          float4 u1 = *reinterpret_cast<const float4*>(ap + (size_t)mt * 16 * CIN + 4);
          float v8[8] = {u0.x, u0.y, u0.z, u0.w, u1.x, u1.y, u1.z, u1.w};
#pragma unroll
          for (int i = 0; i < 8; ++i) {
            vs[i] += v8[i];
            af[mt][i] = (short)f2bf(v8[i]);
          }
        }
      } else {
        const int c0 = kt * 32 + lk * 8;
        const float4 s0 = *reinterpret_cast<const float4*>(&sScale[c0]);
        const float4 s1 = *reinterpret_cast<const float4*>(&sScale[c0 + 4]);
        const float4 h0 = *reinterpret_cast<const float4*>(&sShift[c0]);
        const float4 h1 = *reinterpret_cast<const float4*>(&sShift[c0 + 4]);
        const float scv[8] = {s0.x, s0.y, s0.z, s0.w, s1.x, s1.y, s1.z, s1.w};
        const float shv[8] = {h0.x, h0.y, h0.z, h0.w, h1.x, h1.y, h1.z, h1.w};
        const bf16x8* yb = reinterpret_cast<const bf16x8*>(inB + (size_t)batch * 8192);
#pragma unroll
        for (int mt = 0; mt < 4; ++mt) {
          bf16x8 r16 = yb[kt * 256 + mt * 64 + l];
#pragma unroll
          for (int i = 0; i < 8; ++i) {
            float hv = fmaxf(fmaf(bf2f((unsigned short)r16[i]), scv[i], shv[i]), 0.f);
            vs[i] += hv;
            af[mt][i] = (short)f2bf(hv);
          }
        }
      }

      bf16x8 asum;
#pragma unroll
      for (int i = 0; i < 8; ++i) asum[i] = (short)f2bf(vs[i]);

      const bf16x8* bI = sBu + kt * 512 + l;
#pragma unroll
      for (int ct = 0; ct < 8; ++ct) {
        bf16x8 fI = bI[ct * 64];
#pragma unroll
        for (int mt = 0; mt < 4; ++mt)
          acc[ct][mt] = __builtin_amdgcn_mfma_f32_16x16x32_bf16(af[mt], fI, acc[ct][mt], 0, 0, 0);
      }
      const bf16x8* bJ = bI + NG;
#pragma unroll
      for (int ct = 0; ct < 8; ++ct)
        accJ[ct] = __builtin_amdgcn_mfma_f32_16x16x32_bf16(asum, bJ[ct * 64], accJ[ct], 0, 0, 0);
    }

    // J vector: colsum over accJ's 16 pseudo-rows
    float jv[8];
#pragma unroll
    for (int ct = 0; ct < 8; ++ct) {
      float t = (accJ[ct][0] + accJ[ct][1]) + (accJ[ct][2] + accJ[ct][3]);
      t += __shfl_xor(t, 16);
      t += __shfl_xor(t, 32);
      jv[ct] = t;
    }

    // ---- epilogue: per-mt 16-row transpose chunks (wave-private) ----
    unsigned short* myT = &sT[w][0];
    float psum[8], psq[8];
#pragma unroll
    for (int ct = 0; ct < 8; ++ct) { psum[ct] = 0.f; psq[ct] = 0.f; }

    bf16x8* yo = reinterpret_cast<bf16x8*>(yout + (size_t)batch * 8192);
#pragma unroll
    for (int mt = 0; mt < 4; ++mt) {
#pragma unroll
      for (int ct = 0; ct < 8; ++ct)
#pragma unroll
        for (int r = 0; r < 4; ++r) {
          float val = acc[ct][mt][r] + jv[ct];
          psum[ct] += val;
          psq[ct]  = fmaf(val, val, psq[ct]);
          myT[(lk * 4 + r) * 136 + ct * 16 + lr] = f2bf(val);
        }
#pragma unroll
      for (int kt2 = 0; kt2 < 4; ++kt2) {
        bf16x8 gd = *reinterpret_cast<const bf16x8*>(&myT[lr * 136 + kt2 * 32 + lk * 8]);
        yo[kt2 * 256 + mt * 64 + l] = gd;
      }
    }

    // per-batch BN partials: reduce over lk with 2 shuffles, store
#pragma unroll
    for (int ct = 0; ct < 8; ++ct) {
      psum[ct] += __shfl_xor(psum[ct], 16);
      psum[ct] += __shfl_xor(psum[ct], 32);
      psq[ct]  += __shfl_xor(psq[ct], 16);
      psq[ct]  += __shfl_xor(psq[ct], 32);
    }
    if (lk == 0) {
      float* pb = part + (size_t)batch * 256;
#pragma unroll
      for (int ct = 0; ct < 8; ++ct) {
        pb[ct * 16 + lr]       = psum[ct];
        pb[128 + ct * 16 + lr] = psq[ct];
      }
    }
  }
}

// ---------------------------------------------------------------------------
// Reduction of part[4096][256] -> scsh[2][128] (two coalesced stages)
// ---------------------------------------------------------------------------
__global__ __launch_bounds__(256) void finA_k(const float* __restrict__ part,
                                              float* __restrict__ pp2)
{
  const int g = blockIdx.x;                     // 0..255
  float s = 0.f;
#pragma unroll
  for (int i = 0; i < 16; ++i)
    s += part[(size_t)(g * 16 + i) * 256 + threadIdx.x];
  pp2[(size_t)g * 256 + threadIdx.x] = s;
}

__global__ __launch_bounds__(1024) void finB_k(const float* __restrict__ pp2,
                                               const float* __restrict__ gam,
                                               const float* __restrict__ bet,
                                               float* __restrict__ scsh)
{
  __shared__ float red[4][256];
  __shared__ float tot[256];
  const int q = threadIdx.x >> 8, t = threadIdx.x & 255;
  float s = 0.f;
#pragma unroll 8
  for (int i = 0; i < 64; ++i)
    s += pp2[(size_t)(q * 64 + i) * 256 + t];
  red[q][t] = s;
  __syncthreads();
  if (q == 0) tot[t] = (red[0][t] + red[1][t]) + (red[2][t] + red[3][t]);
  __syncthreads();
  if (threadIdx.x < 128) {
    float mu  = tot[threadIdx.x] * INV_NROWS;
    float var = tot[128 + threadIdx.x] * INV_NROWS - mu * mu;
    float rs  = rsqrtf(var + 1e-5f);
    float sc  = gam[threadIdx.x] * rs;
    scsh[threadIdx.x]       = sc;
    scsh[128 + threadIdx.x] = fmaf(-mu, sc, bet[threadIdx.x]);
  }
}

// ---------------------------------------------------------------------------
// Final BN + ReLU + mean over nodes (reads bf16 granules, uses scsh)
// ---------------------------------------------------------------------------
__global__ __launch_bounds__(256) void pool_k(const unsigned short* __restrict__ y,
                                              const float* __restrict__ scsh,
                                              float* __restrict__ out)
{
  __shared__ float sYp[64][132];
  __shared__ float sPool[2][DCH];
  const int b = blockIdx.x;
  const int t = threadIdx.x;
  const int wv = t >> 6, l = t & 63;
  const int row = wv * 16 + (l & 15);

#pragma unroll
  for (int kt = 0; kt < 4; ++kt) {
    bf16x8 r16 = *(reinterpret_cast<const bf16x8*>(y + (size_t)b * 8192) + (kt * 256 + t));
    const int feat = kt * 32 + (l >> 4) * 8;
    float4 f0, f1;
    f0.x = bf2f((unsigned short)r16[0]); f0.y = bf2f((unsigned short)r16[1]);
    f0.z = bf2f((unsigned short)r16[2]); f0.w = bf2f((unsigned short)r16[3]);
    f1.x = bf2f((unsigned short)r16[4]); f1.y = bf2f((unsigned short)r16[5]);
    f1.z = bf2f((unsigned short)r16[6]); f1.w = bf2f((unsigned short)r16[7]);
    *reinterpret_cast<float4*>(&sYp[row][feat])     = f0;
    *reinterpret_cast<float4*>(&sYp[row][feat + 4]) = f1;
  }
  __syncthreads();
  {
    const int c = t & 127, rg = t >> 7;
    float sc = scsh[c];
    float sh = scsh[128 + c];
    float s = 0.f;
#pragma unroll 8
    for (int r = rg * 32; r < rg * 32 + 32; ++r)
      s += fmaxf(fmaf(sYp[r][c], sc, sh), 0.f);
    sPool[rg][c] = s;
  }
  __syncthreads();
  if (t < DCH)
    out[(size_t)b * DCH + t] = (sPool[0][t] + sPool[1][t]) * (1.0f / 64.0f);
}

// ---------------------------------------------------------------------------
extern "C" void kernel_launch(void* const* d_in, const int* in_sizes, int n_in,
                              void* d_out, int out_size, void* d_ws, size_t ws_size,
                              hipStream_t stream)
{
  const float* x  = (const float*)d_in[0];
  const float* W1 = (const float*)d_in[1];
  const float* W2 = (const float*)d_in[2];
  const float* W3 = (const float*)d_in[3];
  const float* g1 = (const float*)d_in[4];
  const float* b1 = (const float*)d_in[5];
  const float* g2 = (const float*)d_in[6];
  const float* b2 = (const float*)d_in[7];
  const float* g3 = (const float*)d_in[8];
  const float* b3 = (const float*)d_in[9];
  float* out = (float*)d_out;
  float* ws  = (float*)d_ws;

  Coeffs co;
  {
    double sd  = sqrt(63.0 / 4095.0);
    double av  = exp(-1.0 / sd);
    double deg = 1.0 + 63.0 * av;
    double al  = -(1.0 - av) / deg;
    double be  = -av / deg;
    double ak[5], bk[5];
    ak[0] = 1.0; bk[0] = 0.0;
    ak[1] = al;  bk[1] = be;
    for (int k = 2; k < 5; ++k) {
      ak[k] = 2.0 * al * ak[k - 1] - ak[k - 2];
      bk[k] = 2.0 * (be * ak[k - 1] + (al + 64.0 * be) * bk[k - 1]) - bk[k - 2];
    }
    for (int k = 0; k < 5; ++k) { co.a[k] = (float)ak[k]; co.b[k] = (float)bk[k]; }
  }

  const unsigned short* gr1 = (const unsigned short*)(ws + OFF_G1);
  const unsigned short* gr2 = (const unsigned short*)(ws + OFF_G2);
  const unsigned short* gr3 = (const unsigned short*)(ws + OFF_G3);
  float* scsh1 = ws + OFF_SCSH;
  float* scsh2 = scsh1 + 256;
  float* scsh3 = scsh1 + 512;
  float* pp2   = ws + OFF_PP2;
  float* pp    = ws + OFF_PART;
  unsigned short* yv = (unsigned short*)(ws + OFF_Y);

  prep_gran<<<64, 256, 0, stream>>>(W1, W2, W3, ws, co);

  layer_k<256, true ><<<256, 256, 0, stream>>>(x, nullptr, yv, gr1, nullptr, pp);
  finA_k<<<256, 256, 0, stream>>>(pp, pp2);
  finB_k<<<1, 1024, 0, stream>>>(pp2, g1, b1, scsh1);
  layer_k<128, false><<<256, 256, 0, stream>>>(nullptr, yv, yv, gr2, scsh1, pp);
  finA_k<<<256, 256, 0, stream>>>(pp, pp2);
  finB_k<<<1, 1024, 0, stream>>>(pp2, g2, b2, scsh2);
  layer_k<128, false><<<256, 256, 0, stream>>>(nullptr, yv, yv, gr3, scsh2, pp);
  finA_k<<<256, 256, 0, stream>>>(pp, pp2);
  finB_k<<<1, 1024, 0, stream>>>(pp2, g3, b3, scsh3);
  pool_k<<<BATCH, 256, 0, stream>>>(yv, scsh3, out);

  (void)in_sizes; (void)n_in; (void)out_size; (void)ws_size;
}